// Round 5
// baseline (695.317 us; speedup 1.0000x reference)
//
#include <hip/hip_runtime.h>

#define BATCH 2048
#define IN_SZ 40960
#define IN4   (IN_SZ / 4)      // 10240 uint4 per row
#define HID   256
#define LCAP  64               // per-row per-perspective capacity (ACTIVE=30 max)
#define TBLK  1280             // transpose blocks (one 32-col strip each)
#define NBA   (TBLK + BATCH)   // kernel A grid

// workspace layout
#define FTT_OFF   0
#define CNT_OFF   (44u * 1024u * 1024u)                 // past 41.9MB ftT
#define LIST_OFF  (CNT_OFF + BATCH * 2 * sizeof(int))

// ---------------------------------------------------------------------------
// Kernel A: transpose + scan in ONE dispatch (disjoint block ranges, no
// interaction -> they overlap; transpose hides under the HBM-bound scan).
//  blocks [0,TBLK):    transpose one 32-wide IN strip of ft_w into ftT.
//  blocks [TBLK,NBA):  scan one batch row (both perspectives), LDS-compact
//                      nonzero feature indices (values are exactly 0.0/1.0,
//                      so integer-bit tests are exact), dump lists to d_ws.
// ---------------------------------------------------------------------------
__global__ __launch_bounds__(256) void prep_scan(
    const float* __restrict__ wo, const float* __restrict__ bo,
    const float* __restrict__ ftw,
    float* __restrict__ ftT,         // [IN_SZ][HID]
    int* __restrict__ cntg,          // [BATCH][2]
    int* __restrict__ listg)         // [BATCH][2][LCAP]
{
    const int t = threadIdx.x;

    if (blockIdx.x < TBLK) {
        // ---- transpose strip: 8 tiles of 32x32, LDS padded ----
        __shared__ float tile[32][33];
        const int bx = blockIdx.x;          // IN strip
        const int tx = t & 31;
        const int ty = t >> 5;              // 0..7
        for (int by = 0; by < 8; ++by) {    // HID tiles
            __syncthreads();                // protect tile from prev iter
#pragma unroll
            for (int j = 0; j < 32; j += 8)
                tile[ty + j][tx] = ftw[(size_t)(by * 32 + ty + j) * IN_SZ + bx * 32 + tx];
            __syncthreads();
#pragma unroll
            for (int j = 0; j < 32; j += 8)
                ftT[(size_t)(bx * 32 + ty + j) * HID + by * 32 + tx] = tile[tx][ty + j];
        }
        return;
    }

    // ---- scan row: deep-unrolled (8 x 16B loads in flight per lane) ----
    __shared__ int idxw[LCAP], idxb[LCAP];
    __shared__ int cntw, cntb;
    const int row = blockIdx.x - TBLK;
    if (t == 0) { cntw = 0; cntb = 0; }
    __syncthreads();

    const uint4* __restrict__ wrow = (const uint4*)(wo + (size_t)row * IN_SZ);
    const uint4* __restrict__ brow = (const uint4*)(bo + (size_t)row * IN_SZ);
#pragma unroll 1
    for (int base = t; base < IN4; base += 1024) {   // 10 iterations
        uint4 W[4], Bv[4];
#pragma unroll
        for (int k = 0; k < 4; ++k) W[k]  = wrow[base + k * 256];
#pragma unroll
        for (int k = 0; k < 4; ++k) Bv[k] = brow[base + k * 256];
#pragma unroll
        for (int k = 0; k < 4; ++k) {
            const int f0 = 4 * (base + k * 256);
            if (W[k].x) idxw[atomicAdd(&cntw, 1)] = f0;
            if (W[k].y) idxw[atomicAdd(&cntw, 1)] = f0 + 1;
            if (W[k].z) idxw[atomicAdd(&cntw, 1)] = f0 + 2;
            if (W[k].w) idxw[atomicAdd(&cntw, 1)] = f0 + 3;
        }
#pragma unroll
        for (int k = 0; k < 4; ++k) {
            const int f0 = 4 * (base + k * 256);
            if (Bv[k].x) idxb[atomicAdd(&cntb, 1)] = f0;
            if (Bv[k].y) idxb[atomicAdd(&cntb, 1)] = f0 + 1;
            if (Bv[k].z) idxb[atomicAdd(&cntb, 1)] = f0 + 2;
            if (Bv[k].w) idxb[atomicAdd(&cntb, 1)] = f0 + 3;
        }
    }
    __syncthreads();

    if (t == 0) { cntg[row * 2] = cntw; cntg[row * 2 + 1] = cntb; }
    if (t < cntw) listg[(row * 2) * LCAP + t] = idxw[t];          // t<256 covers LCAP
    if (t < cntb) listg[(row * 2 + 1) * LCAP + t] = idxb[t];
}

// ---------------------------------------------------------------------------
// Kernel B: per-row FT gather (coalesced 1KB ftT rows, L3-resident) + MLP.
// ---------------------------------------------------------------------------
__global__ __launch_bounds__(256) void gather_mlp(
    const int* __restrict__ cntg, const int* __restrict__ listg,
    const float* __restrict__ stm,
    const float* __restrict__ ftT, const float* __restrict__ ftb,
    const float* __restrict__ l1w, const float* __restrict__ l1b,
    const float* __restrict__ l2w, const float* __restrict__ l2b,
    const float* __restrict__ l3w, const float* __restrict__ l3b,
    float* __restrict__ out)
{
    __shared__ int   sidx[2 * LCAP];
    __shared__ float hidden[2 * HID];
    __shared__ float x1[32], x2[32];

    const int b = blockIdx.x;
    const int t = threadIdx.x;

    if (t < 2 * LCAP) sidx[t] = listg[b * 2 * LCAP + t];
    __syncthreads();

    const int cw = cntg[b * 2 + 0];
    const int cb = cntg[b * 2 + 1];

    float accw = ftb[t];
    float accb = accw;
    for (int j = 0; j < cw; ++j) accw += ftT[(size_t)sidx[j] * HID + t];
    for (int j = 0; j < cb; ++j) accb += ftT[(size_t)sidx[LCAP + j] * HID + t];
    accw = fminf(fmaxf(accw, 0.f), 1.f);
    accb = fminf(fmaxf(accb, 0.f), 1.f);

    const bool s = (stm[b] != 0.f);
    hidden[t]       = s ? accw : accb;
    hidden[HID + t] = s ? accb : accw;
    __syncthreads();

    // l1 (512 -> 32): 8 lanes per output, shuffle reduce
    {
        const int o = t >> 3;
        const int part = t & 7;
        const float* w1p = l1w + o * (2 * HID);
        float sum = 0.f;
#pragma unroll 8
        for (int i = part; i < 2 * HID; i += 8)
            sum += hidden[i] * w1p[i];
        sum += __shfl_xor(sum, 1);
        sum += __shfl_xor(sum, 2);
        sum += __shfl_xor(sum, 4);
        if (part == 0) x1[o] = fminf(fmaxf(sum + l1b[o], 0.f), 1.f);
    }
    __syncthreads();

    // l2 (32 -> 32)
    if (t < 32) {
        const float* w2 = l2w + t * 32;
        float sum = l2b[t];
#pragma unroll
        for (int i = 0; i < 32; ++i) sum += x1[i] * w2[i];
        x2[t] = fminf(fmaxf(sum, 0.f), 1.f);
    }
    __syncthreads();

    // l3 (32 -> 1)
    if (t == 0) {
        float sum = l3b[0];
#pragma unroll
        for (int i = 0; i < 32; ++i) sum += x2[i] * l3w[i];
        out[b] = sum;
    }
}

// ---------------------------------------------------------------------------
// Fallback (ws too small): fully fused, untransposed strided gather.
// ---------------------------------------------------------------------------
__global__ __launch_bounds__(256) void nnue_fused_fallback(
    const float* __restrict__ wo, const float* __restrict__ bo,
    const float* __restrict__ stm,
    const float* __restrict__ ftw, const float* __restrict__ ftb,
    const float* __restrict__ l1w, const float* __restrict__ l1b,
    const float* __restrict__ l2w, const float* __restrict__ l2b,
    const float* __restrict__ l3w, const float* __restrict__ l3b,
    float* __restrict__ out) {
    __shared__ int   idxw[LCAP], idxb[LCAP];
    __shared__ int   cntw, cntb;
    __shared__ float hidden[2 * HID];
    __shared__ float x1[32], x2[32];

    const int b = blockIdx.x;
    const int t = threadIdx.x;
    if (t == 0) { cntw = 0; cntb = 0; }
    __syncthreads();

    const uint4* wrow = (const uint4*)(wo + (size_t)b * IN_SZ);
    const uint4* brow = (const uint4*)(bo + (size_t)b * IN_SZ);
    for (int i = t; i < IN4; i += 256) {
        uint4 v = wrow[i];
        uint4 u = brow[i];
        if (v.x | v.y | v.z | v.w) {
            if (v.x) idxw[atomicAdd(&cntw, 1)] = 4 * i;
            if (v.y) idxw[atomicAdd(&cntw, 1)] = 4 * i + 1;
            if (v.z) idxw[atomicAdd(&cntw, 1)] = 4 * i + 2;
            if (v.w) idxw[atomicAdd(&cntw, 1)] = 4 * i + 3;
        }
        if (u.x | u.y | u.z | u.w) {
            if (u.x) idxb[atomicAdd(&cntb, 1)] = 4 * i;
            if (u.y) idxb[atomicAdd(&cntb, 1)] = 4 * i + 1;
            if (u.z) idxb[atomicAdd(&cntb, 1)] = 4 * i + 2;
            if (u.w) idxb[atomicAdd(&cntb, 1)] = 4 * i + 3;
        }
    }
    __syncthreads();

    float accw = ftb[t], accb = accw;
    for (int j = 0; j < cntw; ++j) accw += ftw[(size_t)t * IN_SZ + idxw[j]];
    for (int j = 0; j < cntb; ++j) accb += ftw[(size_t)t * IN_SZ + idxb[j]];
    accw = fminf(fmaxf(accw, 0.f), 1.f);
    accb = fminf(fmaxf(accb, 0.f), 1.f);

    const bool s = (stm[b] != 0.f);
    hidden[t]       = s ? accw : accb;
    hidden[HID + t] = s ? accb : accw;
    __syncthreads();

    {
        const int o = t >> 3, part = t & 7;
        const float* w1p = l1w + o * (2 * HID);
        float sum = 0.f;
        for (int i = part; i < 2 * HID; i += 8) sum += hidden[i] * w1p[i];
        sum += __shfl_xor(sum, 1);
        sum += __shfl_xor(sum, 2);
        sum += __shfl_xor(sum, 4);
        if (part == 0) x1[o] = fminf(fmaxf(sum + l1b[o], 0.f), 1.f);
    }
    __syncthreads();
    if (t < 32) {
        float sum = l2b[t];
        for (int i = 0; i < 32; ++i) sum += x1[i] * l2w[t * 32 + i];
        x2[t] = fminf(fmaxf(sum, 0.f), 1.f);
    }
    __syncthreads();
    if (t == 0) {
        float sum = l3b[0];
        for (int i = 0; i < 32; ++i) sum += x2[i] * l3w[i];
        out[b] = sum;
    }
}

extern "C" void kernel_launch(void* const* d_in, const int* in_sizes, int n_in,
                              void* d_out, int out_size, void* d_ws, size_t ws_size,
                              hipStream_t stream) {
    const float* wo  = (const float*)d_in[0];
    const float* bo  = (const float*)d_in[1];
    const float* stm = (const float*)d_in[2];
    const float* ftw = (const float*)d_in[3];
    const float* ftb = (const float*)d_in[4];
    const float* l1w = (const float*)d_in[5];
    const float* l1b = (const float*)d_in[6];
    const float* l2w = (const float*)d_in[7];
    const float* l2b = (const float*)d_in[8];
    const float* l3w = (const float*)d_in[9];
    const float* l3b = (const float*)d_in[10];
    float* out = (float*)d_out;

    const size_t need = LIST_OFF + (size_t)BATCH * 2 * LCAP * sizeof(int);
    if (ws_size >= need) {
        float* ftT  = (float*)((char*)d_ws + FTT_OFF);
        int* cntg   = (int*)((char*)d_ws + CNT_OFF);
        int* listg  = (int*)((char*)d_ws + LIST_OFF);

        prep_scan<<<NBA, 256, 0, stream>>>(wo, bo, ftw, ftT, cntg, listg);
        gather_mlp<<<BATCH, 256, 0, stream>>>(cntg, listg, stm, ftT, ftb,
                                              l1w, l1b, l2w, l2b, l3w, l3b, out);
    } else {
        nnue_fused_fallback<<<BATCH, 256, 0, stream>>>(wo, bo, stm, ftw, ftb,
                                                       l1w, l1b, l2w, l2b, l3w, l3b, out);
    }
}